// Round 4
// baseline (455.278 us; speedup 1.0000x reference)
//
#include <hip/hip_runtime.h>
#include <math.h>

#define NN  1024
#define NB  8
#define RPW 8     // rows of X per wave
#define TPB 256

// ---- cross-lane exchange primitives (partner lane = lane ^ (M/16)) ----
template<int CTRL>
__device__ __forceinline__ float dpp_xor(float y) {
    int i = __builtin_bit_cast(int, y);
    i = __builtin_amdgcn_update_dpp(i, i, CTRL, 0xF, 0xF, false);
    return __builtin_bit_cast(float, i);
}
template<int OFF>
__device__ __forceinline__ float swz_xor(float y) {
    int i = __builtin_bit_cast(int, y);
    i = __builtin_amdgcn_ds_swizzle(i, OFF);
    return __builtin_bit_cast(float, i);
}
template<int M> __device__ __forceinline__ float shuf(float y) {
    if constexpr      (M == 16)  return dpp_xor<0xB1>(y);      // lane^1
    else if constexpr (M == 32)  return dpp_xor<0x4E>(y);      // lane^2
    else if constexpr (M == 64)  return swz_xor<0x101F>(y);    // lane^4
    else if constexpr (M == 128) return swz_xor<0x201F>(y);    // lane^8
    else if constexpr (M == 256) return swz_xor<0x401F>(y);    // lane^16
    else                         return __shfl_xor(y, 32, 64); // lane^32
}

__device__ __forceinline__ float sigm(float d) {
    const float ad = fabsf(d) + 1e-10f;
    const float pw = __expf(-0.25f * __logf(ad));   // (|d|+eps)^-0.25
    const float z  = d * 10.0f * pw;
    return 1.0f / (1.0f + __expf(-z));
}

// ---- one bitonic layer, fully compile-time (BLK,SUB) ----
// Per-column alpha: d = v_b - v_a (direction-corrected); SAME alpha at both
// ends; new_c = alpha*v_c + (1-alpha)*v_q  (verified identical to reference).
template<int BLK, int SUB>
__device__ __forceinline__ void do_layer(float (&x)[16], float (&v)[RPW][16],
                                         int lane, int c0) {
    constexpr int S = BLK - SUB;
    constexpr int M = 1 << S;
    constexpr int T = BLK + 1;
    float al[16];

    if constexpr (M <= 8) {
        // ---- alpha + x: 8 in-lane pairs ----
        #pragma unroll
        for (int pi = 0; pi < 8; ++pi) {
            const int jl = ((pi >> S) << (S + 1)) | (pi & (M - 1));
            const int jh = jl | M;
            const float lo = x[jl], hi = x[jh];
            const float dv = hi - lo;
            const int  sw  = ((c0 + jl) >> T) & 1;   // direction bit
            const float d  = __builtin_bit_cast(float,
                               __builtin_bit_cast(int, dv) ^ (sw << 31));
            const float a  = sigm(d);
            al[jl] = a; al[jh] = a;
            x[jl] = fmaf(-a, dv, hi);   // a*lo + (1-a)*hi
            x[jh] = fmaf( a, dv, lo);   // (1-a)*lo + a*hi
        }
        // ---- rows: pair-form, 3 VALU per pair ----
        #pragma unroll
        for (int r = 0; r < RPW; ++r) {
            #pragma unroll
            for (int pi = 0; pi < 8; ++pi) {
                const int jl = ((pi >> S) << (S + 1)) | (pi & (M - 1));
                const int jh = jl | M;
                const float dv = v[r][jh] - v[r][jl];
                const float a  = al[jl];
                const float lo = v[r][jl];
                v[r][jl] = fmaf(-a, dv, v[r][jh]);
                v[r][jh] = fmaf( a, dv, lo);
            }
        }
    } else {
        // bit s and bit t of c come from the lane index (s,t >= 4);
        // lane>>6 == 0 handles t=10 automatically.
        const int bit  = (lane >> (S - 4)) & 1;
        const int sw   = (lane >> (T - 4)) & 1;
        const int flip = (bit ^ sw) << 31;           // flip iff c is the 'b' end
        #pragma unroll
        for (int j = 0; j < 16; ++j) {
            const float xq = shuf<M>(x[j]);
            const float dv = xq - x[j];
            const float d  = __builtin_bit_cast(float,
                               __builtin_bit_cast(int, dv) ^ flip);
            const float a  = sigm(d);
            al[j] = a;
            x[j]  = fmaf(a, x[j] - xq, xq);
        }
        #pragma unroll
        for (int r = 0; r < RPW; ++r)
            #pragma unroll
            for (int j = 0; j < 16; ++j) {
                const float p = shuf<M>(v[r][j]);
                v[r][j] = fmaf(al[j], v[r][j] - p, p);
            }
    }
}

__global__ __launch_bounds__(TPB, 1) void diffsort_reg(
    const float* __restrict__ vecs,   // [NB][NN]
    float*       __restrict__ out)    // [NB*NN] x, then [NB][NN][NN] X
{
    const int tid   = threadIdx.x;
    const int lane  = tid & 63;
    const int wave  = tid >> 6;
    const int w     = blockIdx.x * 4 + wave;   // 1024 waves total
    const int batch = w >> 7;                  // 128 waves per batch
    const int wb    = w & 127;
    const int r0    = wb * RPW;
    const int c0    = lane * 16;

    float x[16];
    {
        const float4* xin = (const float4*)(vecs + batch * NN + c0);
        *(float4*)&x[0]  = xin[0];
        *(float4*)&x[4]  = xin[1];
        *(float4*)&x[8]  = xin[2];
        *(float4*)&x[12] = xin[3];
    }

    float v[RPW][16];
    #pragma unroll
    for (int r = 0; r < RPW; ++r)
        #pragma unroll
        for (int j = 0; j < 16; ++j)
            v[r][j] = (c0 + j == r0 + r) ? 1.0f : 0.0f;

    #define L(b, s) do_layer<b, s>(x, v, lane, c0);
    L(0,0)
    L(1,0) L(1,1)
    L(2,0) L(2,1) L(2,2)
    L(3,0) L(3,1) L(3,2) L(3,3)
    L(4,0) L(4,1) L(4,2) L(4,3) L(4,4)
    L(5,0) L(5,1) L(5,2) L(5,3) L(5,4) L(5,5)
    L(6,0) L(6,1) L(6,2) L(6,3) L(6,4) L(6,5) L(6,6)
    L(7,0) L(7,1) L(7,2) L(7,3) L(7,4) L(7,5) L(7,6) L(7,7)
    L(8,0) L(8,1) L(8,2) L(8,3) L(8,4) L(8,5) L(8,6) L(8,7) L(8,8)
    L(9,0) L(9,1) L(9,2) L(9,3) L(9,4) L(9,5) L(9,6) L(9,7) L(9,8) L(9,9)
    #undef L

    // ---- x output: one wave per batch writes it ----
    if (wb == 0) {
        float* xo = out + batch * NN + c0;
        *(float4*)&xo[0]  = *(float4*)&x[0];
        *(float4*)&xo[4]  = *(float4*)&x[4];
        *(float4*)&xo[8]  = *(float4*)&x[8];
        *(float4*)&xo[12] = *(float4*)&x[12];
    }

    // ---- X rows ----
    float* Xo = out + (size_t)NB * NN + (size_t)batch * NN * NN;
    #pragma unroll
    for (int r = 0; r < RPW; ++r) {
        float* rowp = Xo + (size_t)(r0 + r) * NN + c0;
        #pragma unroll
        for (int q = 0; q < 4; ++q) {
            float4 s4 = make_float4(v[r][4*q+0], v[r][4*q+1],
                                    v[r][4*q+2], v[r][4*q+3]);
            *(float4*)&rowp[4*q] = s4;
        }
    }
}

extern "C" void kernel_launch(void* const* d_in, const int* in_sizes, int n_in,
                              void* d_out, int out_size, void* d_ws, size_t ws_size,
                              hipStream_t stream) {
    const float* vecs = (const float*)d_in[0];
    float*       out  = (float*)d_out;
    diffsort_reg<<<NB * 32, TPB, 0, stream>>>(vecs, out);   // 256 blocks x 4 waves
}

// Round 5
// 180.358 us; speedup vs baseline: 2.5243x; 2.5243x over previous
//
#include <hip/hip_runtime.h>
#include <math.h>

#define NN      1024
#define NB      8
#define NLAYERS 55

// ---- cross-lane exchange primitives (partner lane = lane ^ (M/16)) ----
template<int CTRL>
__device__ __forceinline__ float dpp_xor(float y) {
    int i = __builtin_bit_cast(int, y);
    i = __builtin_amdgcn_update_dpp(i, i, CTRL, 0xF, 0xF, false);
    return __builtin_bit_cast(float, i);
}
template<int OFF>
__device__ __forceinline__ float swz_xor(float y) {
    int i = __builtin_bit_cast(int, y);
    i = __builtin_amdgcn_ds_swizzle(i, OFF);
    return __builtin_bit_cast(float, i);
}
template<int M> __device__ __forceinline__ float shuf(float y) {
    if constexpr      (M == 16)  return dpp_xor<0xB1>(y);      // lane^1
    else if constexpr (M == 32)  return dpp_xor<0x4E>(y);      // lane^2
    else if constexpr (M == 64)  return swz_xor<0x101F>(y);    // lane^4
    else if constexpr (M == 128) return swz_xor<0x201F>(y);    // lane^8
    else if constexpr (M == 256) return swz_xor<0x401F>(y);    // lane^16
    else                         return __shfl_xor(y, 32, 64); // lane^32
}

__device__ __forceinline__ float bxor(float v, int mask) {
    return __builtin_bit_cast(float, __builtin_bit_cast(int, v) ^ mask);
}

__device__ __forceinline__ float sigm(float d) {
    const float ad = fabsf(d) + 1e-10f;
    const float pw = __expf(-0.25f * __logf(ad));   // (|d|+eps)^-0.25
    const float z  = d * 10.0f * pw;
    return 1.0f / (1.0f + __expf(-z));
}

// ================= Producer: x evolution + per-column alpha =================
// One wave per batch. alpha layout (coalesced both sides):
//   column c = lane*16 + 4q + u  ->  al_g[(batch*NLAYERS+l)*NN + q*256 + lane*4 + u]
template<int BLK, int SUB>
__device__ __forceinline__ void alpha_layer(float (&x)[16], float (&al)[16],
                                            int lane, int c0) {
    constexpr int S = BLK - SUB;
    constexpr int M = 1 << S;
    constexpr int T = BLK + 1;
    if constexpr (M <= 8) {
        #pragma unroll
        for (int pi = 0; pi < 8; ++pi) {
            const int jl = ((pi >> S) << (S + 1)) | (pi & (M - 1));
            const int jh = jl | M;
            const float lo = x[jl], hi = x[jh];
            const float dv = hi - lo;
            const int  sw  = ((c0 + jl) >> T) & 1;      // direction bit
            const float d  = bxor(dv, sw << 31);        // = v_b - v_a
            const float a  = sigm(d);
            al[jl] = a; al[jh] = a;
            x[jl] = fmaf(-a, dv, hi);   // a*lo + (1-a)*hi
            x[jh] = fmaf( a, dv, lo);   // (1-a)*lo + a*hi
        }
    } else {
        const int bit  = (lane >> (S - 4)) & 1;   // bit S of c
        const int sw   = (lane >> (T - 4)) & 1;   // bit T of c (T=10 -> 0)
        const int flip = (bit ^ sw) << 31;
        #pragma unroll
        for (int j = 0; j < 16; ++j) {
            const float xq = shuf<M>(x[j]);
            const float dv = xq - x[j];
            const float d  = bxor(dv, flip);
            const float a  = sigm(d);
            al[j] = a;
            x[j]  = fmaf(a, x[j] - xq, xq);
        }
    }
}

__global__ __launch_bounds__(64) void diffsort_alpha_reg(
    const float* __restrict__ vecs,   // [NB][NN]
    float*       __restrict__ out,    // x -> out[0 .. NB*NN)
    float*       __restrict__ al_g)   // [NB][NLAYERS][NN] (q-major layout)
{
    const int lane  = threadIdx.x;
    const int batch = blockIdx.x;
    const int c0    = lane * 16;

    float x[16];
    {
        const float4* xin = (const float4*)(vecs + batch * NN + c0);
        *(float4*)&x[0]  = xin[0];
        *(float4*)&x[4]  = xin[1];
        *(float4*)&x[8]  = xin[2];
        *(float4*)&x[12] = xin[3];
    }

    float al[16];
    int layer = 0;
    #define L(b, s)                                                          \
    {                                                                        \
        alpha_layer<b, s>(x, al, lane, c0);                                  \
        float* ap = al_g + (size_t)(batch * NLAYERS + layer) * NN + lane*4;  \
        *(float4*)&ap[0]   = *(float4*)&al[0];                               \
        *(float4*)&ap[256] = *(float4*)&al[4];                               \
        *(float4*)&ap[512] = *(float4*)&al[8];                               \
        *(float4*)&ap[768] = *(float4*)&al[12];                              \
        ++layer;                                                             \
    }
    L(0,0)
    L(1,0) L(1,1)
    L(2,0) L(2,1) L(2,2)
    L(3,0) L(3,1) L(3,2) L(3,3)
    L(4,0) L(4,1) L(4,2) L(4,3) L(4,4)
    L(5,0) L(5,1) L(5,2) L(5,3) L(5,4) L(5,5)
    L(6,0) L(6,1) L(6,2) L(6,3) L(6,4) L(6,5) L(6,6)
    L(7,0) L(7,1) L(7,2) L(7,3) L(7,4) L(7,5) L(7,6) L(7,7)
    L(8,0) L(8,1) L(8,2) L(8,3) L(8,4) L(8,5) L(8,6) L(8,7) L(8,8)
    L(9,0) L(9,1) L(9,2) L(9,3) L(9,4) L(9,5) L(9,6) L(9,7) L(9,8) L(9,9)
    #undef L

    float* xo = out + batch * NN + c0;
    *(float4*)&xo[0]  = *(float4*)&x[0];
    *(float4*)&xo[4]  = *(float4*)&x[4];
    *(float4*)&xo[8]  = *(float4*)&x[8];
    *(float4*)&xo[12] = *(float4*)&x[12];
}

// ================= Consumer: propagate X rows (direction-agnostic) =========
// new_c = al_c * v_c + (1 - al_c) * v_partner  -- same al at both pair ends.
template<int S>
__device__ __forceinline__ void inlane(float (&v)[4][16], const float (&al)[16]) {
    constexpr int M = 1 << S;
    #pragma unroll
    for (int r = 0; r < 4; ++r)
        #pragma unroll
        for (int pi = 0; pi < 8; ++pi) {
            const int jl = ((pi >> S) << (S + 1)) | (pi & (M - 1));
            const int jh = jl | M;
            const float dv = v[r][jh] - v[r][jl];
            const float a  = al[jl];               // == al[jh]
            const float lo = v[r][jl];
            v[r][jl] = fmaf(-a, dv, v[r][jh]);     // a*lo + (1-a)*hi
            v[r][jh] = fmaf( a, dv, lo);           // (1-a)*lo + a*hi
        }
}
template<int M>
__device__ __forceinline__ void cross(float (&v)[4][16], const float (&al)[16]) {
    #pragma unroll
    for (int r = 0; r < 4; ++r)
        #pragma unroll
        for (int j = 0; j < 16; ++j) {
            const float p = shuf<M>(v[r][j]);
            v[r][j] = fmaf(al[j], v[r][j] - p, p);
        }
}

__global__ __launch_bounds__(256, 2) void diffsort_rows(
    const float* __restrict__ al_g,
    float*       __restrict__ out)
{
    const int tid   = threadIdx.x;
    const int lane  = tid & 63;
    const int wave  = tid >> 6;
    const int w     = blockIdx.x * 4 + wave;   // 2048 waves
    const int batch = w >> 8;                  // 256 waves per batch
    const int wb    = w & 255;
    const int r0    = wb * 4;                  // 4 rows per wave
    const int c0    = lane * 16;

    float v[4][16];
    #pragma unroll
    for (int r = 0; r < 4; ++r)
        #pragma unroll
        for (int j = 0; j < 16; ++j)
            v[r][j] = (c0 + j == r0 + r) ? 1.0f : 0.0f;

    const float* ab = al_g + (size_t)batch * NLAYERS * NN + lane * 4;

    float al[16];
    #pragma unroll
    for (int q = 0; q < 4; ++q)
        *(float4*)&al[q * 4] = *(const float4*)&ab[q * 256];

    int layer = 0;
    #pragma unroll 1
    for (int blk = 0; blk < 10; ++blk) {
        #pragma unroll 1
        for (int sub = 0; sub <= blk; ++sub, ++layer) {
            float aln[16];
            if (layer < NLAYERS - 1) {                       // prefetch next layer
                const float* ap = ab + (size_t)(layer + 1) * NN;
                #pragma unroll
                for (int q = 0; q < 4; ++q)
                    *(float4*)&aln[q * 4] = *(const float4*)&ap[q * 256];
            }
            const int m = 1 << (blk - sub);
            switch (m) {
                case 1:   inlane<0>(v, al);  break;
                case 2:   inlane<1>(v, al);  break;
                case 4:   inlane<2>(v, al);  break;
                case 8:   inlane<3>(v, al);  break;
                case 16:  cross<16>(v, al);  break;
                case 32:  cross<32>(v, al);  break;
                case 64:  cross<64>(v, al);  break;
                case 128: cross<128>(v, al); break;
                case 256: cross<256>(v, al); break;
                default:  cross<512>(v, al); break;
            }
            if (layer < NLAYERS - 1) {
                #pragma unroll
                for (int j = 0; j < 16; ++j) al[j] = aln[j];
            }
        }
    }

    float* Xo = out + (size_t)NB * NN + (size_t)batch * NN * NN;
    #pragma unroll
    for (int r = 0; r < 4; ++r) {
        float* rowp = Xo + (size_t)(r0 + r) * NN + c0;
        #pragma unroll
        for (int q = 0; q < 4; ++q) {
            float4 s4 = make_float4(v[r][4*q+0], v[r][4*q+1],
                                    v[r][4*q+2], v[r][4*q+3]);
            *(float4*)&rowp[4*q] = s4;
        }
    }
}

extern "C" void kernel_launch(void* const* d_in, const int* in_sizes, int n_in,
                              void* d_out, int out_size, void* d_ws, size_t ws_size,
                              hipStream_t stream) {
    const float* vecs = (const float*)d_in[0];
    float*       out  = (float*)d_out;
    float*       al_g = (float*)d_ws;    // NB*NLAYERS*NN*4 = 1.80 MB

    diffsort_alpha_reg<<<NB, 64, 0, stream>>>(vecs, out, al_g);
    diffsort_rows<<<NB * 64, 256, 0, stream>>>(al_g, out);
}

// Round 6
// 178.037 us; speedup vs baseline: 2.5572x; 1.0130x over previous
//
#include <hip/hip_runtime.h>
#include <math.h>

#define NN      1024
#define NB      8
#define NLAYERS 55

// ---- cross-lane exchange primitives (partner lane = lane ^ (M/16)) ----
template<int CTRL>
__device__ __forceinline__ float dpp_xor(float y) {
    int i = __builtin_bit_cast(int, y);
    i = __builtin_amdgcn_update_dpp(i, i, CTRL, 0xF, 0xF, false);
    return __builtin_bit_cast(float, i);
}
template<int OFF>
__device__ __forceinline__ float swz_xor(float y) {
    int i = __builtin_bit_cast(int, y);
    i = __builtin_amdgcn_ds_swizzle(i, OFF);
    return __builtin_bit_cast(float, i);
}
template<int M> __device__ __forceinline__ float shuf(float y) {
    if constexpr      (M == 16)  return dpp_xor<0xB1>(y);      // lane^1
    else if constexpr (M == 32)  return dpp_xor<0x4E>(y);      // lane^2
    else if constexpr (M == 64)  return swz_xor<0x101F>(y);    // lane^4
    else if constexpr (M == 128) return swz_xor<0x201F>(y);    // lane^8
    else if constexpr (M == 256) return swz_xor<0x401F>(y);    // lane^16
    else                         return __shfl_xor(y, 32, 64); // lane^32
}

__device__ __forceinline__ float bxor(float v, int mask) {
    return __builtin_bit_cast(float, __builtin_bit_cast(int, v) ^ mask);
}
__device__ __forceinline__ float sigm(float d) {
    const float ad = fabsf(d) + 1e-10f;
    const float pw = __expf(-0.25f * __logf(ad));   // (|d|+eps)^-0.25
    const float z  = d * 10.0f * pw;
    return 1.0f / (1.0f + __expf(-z));
}

// ================= Producer: one wave per batch, rolled loop ================
// x in registers (16 cols/lane); alpha written per layer as 4 coalesced
// dwordx4/lane (fire-and-forget, NO barriers anywhere).
template<int S>
__device__ __forceinline__ void axl(float (&x)[16], float (&alv)[16],
                                    int c0, int t) {
    constexpr int M = 1 << S;
    #pragma unroll
    for (int pi = 0; pi < 8; ++pi) {
        const int jl = ((pi >> S) << (S + 1)) | (pi & (M - 1));
        const int jh = jl | M;
        const float lo = x[jl], hi = x[jh];
        const float dv = hi - lo;
        const int  sw  = ((c0 + jl) >> t) & 1;     // direction bit of column
        const float a  = sigm(bxor(dv, sw << 31)); // = sigm(v_b - v_a)
        alv[jl] = a; alv[jh] = a;
        x[jl] = fmaf(-a, dv, hi);   // a*lo + (1-a)*hi
        x[jh] = fmaf( a, dv, lo);   // (1-a)*lo + a*hi
    }
}
template<int M>
__device__ __forceinline__ void axc(float (&x)[16], float (&alv)[16],
                                    int lane, int t) {
    constexpr int S4 = (M == 16) ? 0 : (M == 32) ? 1 : (M == 64) ? 2 :
                       (M == 128) ? 3 : (M == 256) ? 4 : 5;   // log2(M)-4
    const int bit  = (lane >> S4) & 1;          // bit S of column
    const int sw   = (lane >> (t - 4)) & 1;     // bit T of column (t=10 -> 0)
    const int flip = (bit ^ sw) << 31;
    #pragma unroll
    for (int j = 0; j < 16; ++j) {
        const float xq = shuf<M>(x[j]);
        const float dv = xq - x[j];
        const float a  = sigm(bxor(dv, flip));
        alv[j] = a;
        x[j]   = fmaf(a, x[j] - xq, xq);
    }
}

__global__ __launch_bounds__(64) void diffsort_alpha_w(
    const float* __restrict__ vecs,   // [NB][NN]
    float*       __restrict__ out,    // x -> out[0 .. NB*NN)
    float*       __restrict__ al_g)   // [NB][NLAYERS][NN], linear
{
    const int lane  = threadIdx.x;
    const int batch = blockIdx.x;
    const int c0    = lane * 16;

    float x[16];
    {
        const float4* xin = (const float4*)(vecs + batch * NN + c0);
        *(float4*)&x[0]  = xin[0];
        *(float4*)&x[4]  = xin[1];
        *(float4*)&x[8]  = xin[2];
        *(float4*)&x[12] = xin[3];
    }

    float* ap = al_g + (size_t)batch * NLAYERS * NN + c0;
    #pragma unroll 1
    for (int blk = 0; blk < 10; ++blk) {
        #pragma unroll 1
        for (int sub = 0; sub <= blk; ++sub) {
            const int s = blk - sub, t = blk + 1;
            float alv[16];
            switch (s) {
                case 0: axl<0>(x, alv, c0, t);    break;
                case 1: axl<1>(x, alv, c0, t);    break;
                case 2: axl<2>(x, alv, c0, t);    break;
                case 3: axl<3>(x, alv, c0, t);    break;
                case 4: axc<16>(x, alv, lane, t); break;
                case 5: axc<32>(x, alv, lane, t); break;
                case 6: axc<64>(x, alv, lane, t); break;
                case 7: axc<128>(x, alv, lane, t);break;
                case 8: axc<256>(x, alv, lane, t);break;
                default:axc<512>(x, alv, lane, t);break;
            }
            *(float4*)&ap[0]  = *(float4*)&alv[0];
            *(float4*)&ap[4]  = *(float4*)&alv[4];
            *(float4*)&ap[8]  = *(float4*)&alv[8];
            *(float4*)&ap[12] = *(float4*)&alv[12];
            ap += NN;
        }
    }

    float* xo = out + batch * NN + c0;
    *(float4*)&xo[0]  = *(float4*)&x[0];
    *(float4*)&xo[4]  = *(float4*)&x[4];
    *(float4*)&xo[8]  = *(float4*)&x[8];
    *(float4*)&xo[12] = *(float4*)&x[12];
}

// ================= Consumer: 2 rows/wave, 16 waves/CU =======================
// Direction-agnostic: new_c = al_c * v_c + (1 - al_c) * v_partner.
template<int S>
__device__ __forceinline__ void inl2(float (&v)[2][16], const float (&al)[16]) {
    constexpr int M = 1 << S;
    #pragma unroll
    for (int r = 0; r < 2; ++r)
        #pragma unroll
        for (int pi = 0; pi < 8; ++pi) {
            const int jl = ((pi >> S) << (S + 1)) | (pi & (M - 1));
            const int jh = jl | M;
            const float dv = v[r][jh] - v[r][jl];
            const float a  = al[jl];               // == al[jh]
            const float lo = v[r][jl];
            v[r][jl] = fmaf(-a, dv, v[r][jh]);
            v[r][jh] = fmaf( a, dv, lo);
        }
}
template<int M>
__device__ __forceinline__ void crs2(float (&v)[2][16], const float (&al)[16]) {
    #pragma unroll
    for (int r = 0; r < 2; ++r)
        #pragma unroll
        for (int j = 0; j < 16; ++j) {
            const float p = shuf<M>(v[r][j]);
            v[r][j] = fmaf(al[j], v[r][j] - p, p);
        }
}

__global__ __launch_bounds__(256) void diffsort_rows2(
    const float* __restrict__ al_g,
    float*       __restrict__ out)
{
    const int tid   = threadIdx.x;
    const int lane  = tid & 63;
    const int wave  = tid >> 6;
    const int w     = blockIdx.x * 4 + wave;   // 4096 waves
    const int batch = w >> 9;                  // 512 waves per batch
    const int wb    = w & 511;
    const int r0    = wb * 2;                  // 2 rows per wave
    const int c0    = lane * 16;

    float v[2][16];
    #pragma unroll
    for (int r = 0; r < 2; ++r)
        #pragma unroll
        for (int j = 0; j < 16; ++j)
            v[r][j] = (c0 + j == r0 + r) ? 1.0f : 0.0f;

    const float* ap = al_g + (size_t)batch * NLAYERS * NN + c0;

    #pragma unroll 1
    for (int blk = 0; blk < 10; ++blk) {
        #pragma unroll 1
        for (int sub = 0; sub <= blk; ++sub) {
            float al[16];
            *(float4*)&al[0]  = *(const float4*)&ap[0];
            *(float4*)&al[4]  = *(const float4*)&ap[4];
            *(float4*)&al[8]  = *(const float4*)&ap[8];
            *(float4*)&al[12] = *(const float4*)&ap[12];
            ap += NN;

            switch (blk - sub) {
                case 0:  inl2<0>(v, al);   break;
                case 1:  inl2<1>(v, al);   break;
                case 2:  inl2<2>(v, al);   break;
                case 3:  inl2<3>(v, al);   break;
                case 4:  crs2<16>(v, al);  break;
                case 5:  crs2<32>(v, al);  break;
                case 6:  crs2<64>(v, al);  break;
                case 7:  crs2<128>(v, al); break;
                case 8:  crs2<256>(v, al); break;
                default: crs2<512>(v, al); break;
            }
        }
    }

    float* Xo = out + (size_t)NB * NN + (size_t)batch * NN * NN;
    #pragma unroll
    for (int r = 0; r < 2; ++r) {
        float* rowp = Xo + (size_t)(r0 + r) * NN + c0;
        #pragma unroll
        for (int q = 0; q < 4; ++q) {
            float4 s4 = make_float4(v[r][4*q+0], v[r][4*q+1],
                                    v[r][4*q+2], v[r][4*q+3]);
            *(float4*)&rowp[4*q] = s4;
        }
    }
}

extern "C" void kernel_launch(void* const* d_in, const int* in_sizes, int n_in,
                              void* d_out, int out_size, void* d_ws, size_t ws_size,
                              hipStream_t stream) {
    const float* vecs = (const float*)d_in[0];
    float*       out  = (float*)d_out;
    float*       al_g = (float*)d_ws;    // NB*NLAYERS*NN*4 = 1.80 MB

    diffsort_alpha_w<<<NB, 64, 0, stream>>>(vecs, out, al_g);
    diffsort_rows2<<<NB * 128, 256, 0, stream>>>(al_g, out);
}

// Round 7
// 143.660 us; speedup vs baseline: 3.1691x; 1.2393x over previous
//
#include <hip/hip_runtime.h>
#include <math.h>

#define NN      1024
#define NB      8
#define NLAYERS 55

// ---- cross-lane exchange primitives ----
template<int CTRL>
__device__ __forceinline__ float dpp_xor(float y) {
    int i = __builtin_bit_cast(int, y);
    i = __builtin_amdgcn_update_dpp(i, i, CTRL, 0xF, 0xF, false);
    return __builtin_bit_cast(float, i);
}
template<int OFF>
__device__ __forceinline__ float swz_xor(float y) {
    int i = __builtin_bit_cast(int, y);
    i = __builtin_amdgcn_ds_swizzle(i, OFF);
    return __builtin_bit_cast(float, i);
}
// shuffle by COLUMN distance M, consumer layout (16 cols/lane): lane ^= M/16
template<int M> __device__ __forceinline__ float shuf(float y) {
    if constexpr      (M == 16)  return dpp_xor<0xB1>(y);      // lane^1
    else if constexpr (M == 32)  return dpp_xor<0x4E>(y);      // lane^2
    else if constexpr (M == 64)  return swz_xor<0x101F>(y);    // lane^4
    else if constexpr (M == 128) return swz_xor<0x201F>(y);    // lane^8
    else if constexpr (M == 256) return swz_xor<0x401F>(y);    // lane^16
    else                         return __shfl_xor(y, 32, 64); // lane^32
}
// shuffle by COLUMN distance M, producer layout (4 cols/lane): lane ^= M/4
template<int M> __device__ __forceinline__ float shufp(float y) {
    if constexpr      (M == 4)   return dpp_xor<0xB1>(y);      // lane^1
    else if constexpr (M == 8)   return dpp_xor<0x4E>(y);      // lane^2
    else if constexpr (M == 16)  return swz_xor<0x101F>(y);    // lane^4
    else if constexpr (M == 32)  return swz_xor<0x201F>(y);    // lane^8
    else if constexpr (M == 64)  return swz_xor<0x401F>(y);    // lane^16
    else                         return __shfl_xor(y, 32, 64); // lane^32
}

__device__ __forceinline__ float bxor(float v, int mask) {
    return __builtin_bit_cast(float, __builtin_bit_cast(int, v) ^ mask);
}
__device__ __forceinline__ float sigm(float d) {
    const float ad = fabsf(d) + 1e-10f;
    const float pw = __expf(-0.25f * __logf(ad));   // (|d|+eps)^-0.25
    const float z  = d * 10.0f * pw;
    return __builtin_amdgcn_rcpf(1.0f + __expf(-z));
}

// ================= Producer: 4 waves/batch, 4 cols/lane =====================
// column c = tid*4 + j. alpha layout linear [batch][layer][col].
__device__ __forceinline__ void pairup(float (&x)[4], float (&alv)[4],
                                       int jl, int jh, int sw) {
    const float lo = x[jl], hi = x[jh];
    const float dv = hi - lo;
    const float a  = sigm(bxor(dv, sw << 31));   // sigm(v_b - v_a)
    alv[jl] = a; alv[jh] = a;
    x[jl] = fmaf(-a, dv, hi);    // a*lo + (1-a)*hi   (min -> a-end value)
    x[jh] = fmaf( a, dv, lo);    // (1-a)*lo + a*hi
}
template<int M>   // column distance, 4..128
__device__ __forceinline__ void crossup(float (&x)[4], float (&alv)[4],
                                        int c0, int t) {
    constexpr int S = (M==4)?2:(M==8)?3:(M==16)?4:(M==32)?5:(M==64)?6:7;
    const int flip = ((((c0 >> S) & 1) ^ ((c0 >> t) & 1)) << 31);
    #pragma unroll
    for (int j = 0; j < 4; ++j) {
        const float xq = shufp<M>(x[j]);
        const float dv = xq - x[j];
        const float a  = sigm(bxor(dv, flip));
        alv[j] = a;
        x[j]   = fmaf(a, x[j] - xq, xq);   // a*v_c + (1-a)*v_q
    }
}

__global__ __launch_bounds__(256) void diffsort_alpha4(
    const float* __restrict__ vecs,   // [NB][NN]
    float*       __restrict__ out,    // x -> out[0 .. NB*NN)
    float*       __restrict__ al_g)   // [NB][NLAYERS][NN]
{
    __shared__ float xs[NN];
    const int tid   = threadIdx.x;
    const int batch = blockIdx.x;
    const int c0    = tid * 4;

    float x[4];
    *(float4*)&x[0] = *(const float4*)(vecs + batch * NN + c0);

    float* ap = al_g + (size_t)batch * NLAYERS * NN + c0;

    #pragma unroll 1
    for (int blk = 0; blk < 10; ++blk) {
        #pragma unroll 1
        for (int sub = 0; sub <= blk; ++sub) {
            const int s = blk - sub, t = blk + 1;
            float alv[4];
            switch (s) {
                case 0:   // pairs (0,1),(2,3) in-lane
                    pairup(x, alv, 0, 1, ((c0 + 0) >> t) & 1);
                    pairup(x, alv, 2, 3, ((c0 + 2) >> t) & 1);
                    break;
                case 1:   // pairs (0,2),(1,3) in-lane
                    pairup(x, alv, 0, 2, ((c0 + 0) >> t) & 1);
                    pairup(x, alv, 1, 3, ((c0 + 1) >> t) & 1);
                    break;
                case 2: crossup<4>  (x, alv, c0, t); break;
                case 3: crossup<8>  (x, alv, c0, t); break;
                case 4: crossup<16> (x, alv, c0, t); break;
                case 5: crossup<32> (x, alv, c0, t); break;
                case 6: crossup<64> (x, alv, c0, t); break;
                case 7: crossup<128>(x, alv, c0, t); break;
                default: {          // s=8,9 -> M=256,512: LDS bounce
                    const int m = 1 << s;
                    __syncthreads();
                    *(float4*)&xs[c0] = *(float4*)&x[0];
                    __syncthreads();
                    float xq[4];
                    *(float4*)&xq[0] = *(const float4*)&xs[c0 ^ m];
                    const int flip = ((((c0 >> s) & 1) ^ ((c0 >> t) & 1)) << 31);
                    #pragma unroll
                    for (int j = 0; j < 4; ++j) {
                        const float dv = xq[j] - x[j];
                        const float a  = sigm(bxor(dv, flip));
                        alv[j] = a;
                        x[j]   = fmaf(a, x[j] - xq[j], xq[j]);
                    }
                } break;
            }
            *(float4*)ap = *(float4*)&alv[0];
            ap += NN;
        }
    }

    *(float4*)(out + batch * NN + c0) = *(float4*)&x[0];
}

// ================= Consumer: 2 rows/wave (unchanged from R6) ================
template<int S>
__device__ __forceinline__ void inl2(float (&v)[2][16], const float (&al)[16]) {
    constexpr int M = 1 << S;
    #pragma unroll
    for (int r = 0; r < 2; ++r)
        #pragma unroll
        for (int pi = 0; pi < 8; ++pi) {
            const int jl = ((pi >> S) << (S + 1)) | (pi & (M - 1));
            const int jh = jl | M;
            const float dv = v[r][jh] - v[r][jl];
            const float a  = al[jl];               // == al[jh]
            const float lo = v[r][jl];
            v[r][jl] = fmaf(-a, dv, v[r][jh]);
            v[r][jh] = fmaf( a, dv, lo);
        }
}
template<int M>
__device__ __forceinline__ void crs2(float (&v)[2][16], const float (&al)[16]) {
    #pragma unroll
    for (int r = 0; r < 2; ++r)
        #pragma unroll
        for (int j = 0; j < 16; ++j) {
            const float p = shuf<M>(v[r][j]);
            v[r][j] = fmaf(al[j], v[r][j] - p, p);
        }
}

__global__ __launch_bounds__(256) void diffsort_rows2(
    const float* __restrict__ al_g,
    float*       __restrict__ out)
{
    const int tid   = threadIdx.x;
    const int lane  = tid & 63;
    const int wave  = tid >> 6;
    const int w     = blockIdx.x * 4 + wave;   // 4096 waves
    const int batch = w >> 9;                  // 512 waves per batch
    const int wb    = w & 511;
    const int r0    = wb * 2;                  // 2 rows per wave
    const int c0    = lane * 16;

    float v[2][16];
    #pragma unroll
    for (int r = 0; r < 2; ++r)
        #pragma unroll
        for (int j = 0; j < 16; ++j)
            v[r][j] = (c0 + j == r0 + r) ? 1.0f : 0.0f;

    const float* ap = al_g + (size_t)batch * NLAYERS * NN + c0;

    #pragma unroll 1
    for (int blk = 0; blk < 10; ++blk) {
        #pragma unroll 1
        for (int sub = 0; sub <= blk; ++sub) {
            float al[16];
            *(float4*)&al[0]  = *(const float4*)&ap[0];
            *(float4*)&al[4]  = *(const float4*)&ap[4];
            *(float4*)&al[8]  = *(const float4*)&ap[8];
            *(float4*)&al[12] = *(const float4*)&ap[12];
            ap += NN;

            switch (blk - sub) {
                case 0:  inl2<0>(v, al);   break;
                case 1:  inl2<1>(v, al);   break;
                case 2:  inl2<2>(v, al);   break;
                case 3:  inl2<3>(v, al);   break;
                case 4:  crs2<16>(v, al);  break;
                case 5:  crs2<32>(v, al);  break;
                case 6:  crs2<64>(v, al);  break;
                case 7:  crs2<128>(v, al); break;
                case 8:  crs2<256>(v, al); break;
                default: crs2<512>(v, al); break;
            }
        }
    }

    float* Xo = out + (size_t)NB * NN + (size_t)batch * NN * NN;
    #pragma unroll
    for (int r = 0; r < 2; ++r) {
        float* rowp = Xo + (size_t)(r0 + r) * NN + c0;
        #pragma unroll
        for (int q = 0; q < 4; ++q) {
            float4 s4 = make_float4(v[r][4*q+0], v[r][4*q+1],
                                    v[r][4*q+2], v[r][4*q+3]);
            *(float4*)&rowp[4*q] = s4;
        }
    }
}

extern "C" void kernel_launch(void* const* d_in, const int* in_sizes, int n_in,
                              void* d_out, int out_size, void* d_ws, size_t ws_size,
                              hipStream_t stream) {
    const float* vecs = (const float*)d_in[0];
    float*       out  = (float*)d_out;
    float*       al_g = (float*)d_ws;    // NB*NLAYERS*NN*4 = 1.80 MB

    diffsort_alpha4<<<NB, 256, 0, stream>>>(vecs, out, al_g);
    diffsort_rows2<<<NB * 128, 256, 0, stream>>>(al_g, out);
}

// Round 8
// 102.941 us; speedup vs baseline: 4.4227x; 1.3956x over previous
//
#include <hip/hip_runtime.h>
#include <math.h>

#define NN      1024
#define NB      8
#define NLAYERS 55

// ---------------- lane-XOR exchange primitives (distance D in lanes) --------
template<int CTRL>
__device__ __forceinline__ float dpp_xor(float y) {
    int i = __builtin_bit_cast(int, y);
    i = __builtin_amdgcn_update_dpp(i, i, CTRL, 0xF, 0xF, false);
    return __builtin_bit_cast(float, i);
}
template<int OFF>
__device__ __forceinline__ float swz_xor(float y) {
    int i = __builtin_bit_cast(int, y);
    i = __builtin_amdgcn_ds_swizzle(i, OFF);
    return __builtin_bit_cast(float, i);
}
template<int D> __device__ __forceinline__ float lshuf(float y) {
    if constexpr      (D == 1)  return dpp_xor<0xB1>(y);       // quad_perm 1,0,3,2
    else if constexpr (D == 2)  return dpp_xor<0x4E>(y);       // quad_perm 2,3,0,1
    else if constexpr (D == 4)  return swz_xor<0x101F>(y);     // xor 4
    else if constexpr (D == 8)  return swz_xor<0x201F>(y);     // xor 8
    else if constexpr (D == 16) return swz_xor<0x401F>(y);     // xor 16
    else                        return __shfl_xor(y, 32, 64);  // lane^32
}
// producer layout shuffles (4 cols/lane, column distance M -> lane ^ M/4)
template<int M> __device__ __forceinline__ float shufp(float y) {
    if constexpr      (M == 4)   return dpp_xor<0xB1>(y);
    else if constexpr (M == 8)   return dpp_xor<0x4E>(y);
    else if constexpr (M == 16)  return swz_xor<0x101F>(y);
    else if constexpr (M == 32)  return swz_xor<0x201F>(y);
    else if constexpr (M == 64)  return swz_xor<0x401F>(y);
    else                         return __shfl_xor(y, 32, 64);
}

__device__ __forceinline__ float bxor(float v, int mask) {
    return __builtin_bit_cast(float, __builtin_bit_cast(int, v) ^ mask);
}
__device__ __forceinline__ float sigm(float d) {
    const float ad = fabsf(d) + 1e-10f;
    const float pw = __expf(-0.25f * __logf(ad));   // (|d|+eps)^-0.25
    const float z  = d * 10.0f * pw;
    return __builtin_amdgcn_rcpf(1.0f + __expf(-z));
}

// ================= Producer (unchanged from R7): 4 waves/batch ==============
__device__ __forceinline__ void pairup(float (&x)[4], float (&alv)[4],
                                       int jl, int jh, int sw) {
    const float lo = x[jl], hi = x[jh];
    const float dv = hi - lo;
    const float a  = sigm(bxor(dv, sw << 31));
    alv[jl] = a; alv[jh] = a;
    x[jl] = fmaf(-a, dv, hi);
    x[jh] = fmaf( a, dv, lo);
}
template<int M>
__device__ __forceinline__ void crossup(float (&x)[4], float (&alv)[4],
                                        int c0, int t) {
    constexpr int S = (M==4)?2:(M==8)?3:(M==16)?4:(M==32)?5:(M==64)?6:7;
    const int flip = ((((c0 >> S) & 1) ^ ((c0 >> t) & 1)) << 31);
    #pragma unroll
    for (int j = 0; j < 4; ++j) {
        const float xq = shufp<M>(x[j]);
        const float dv = xq - x[j];
        const float a  = sigm(bxor(dv, flip));
        alv[j] = a;
        x[j]   = fmaf(a, x[j] - xq, xq);
    }
}

__global__ __launch_bounds__(256) void diffsort_alpha4(
    const float* __restrict__ vecs,
    float*       __restrict__ out,
    float*       __restrict__ al_g)   // [NB][NLAYERS][NN]
{
    __shared__ float xs[NN];
    const int tid   = threadIdx.x;
    const int batch = blockIdx.x;
    const int c0    = tid * 4;

    float x[4];
    *(float4*)&x[0] = *(const float4*)(vecs + batch * NN + c0);

    float* ap = al_g + (size_t)batch * NLAYERS * NN + c0;

    #pragma unroll 1
    for (int blk = 0; blk < 10; ++blk) {
        #pragma unroll 1
        for (int sub = 0; sub <= blk; ++sub) {
            const int s = blk - sub, t = blk + 1;
            float alv[4];
            switch (s) {
                case 0:
                    pairup(x, alv, 0, 1, ((c0 + 0) >> t) & 1);
                    pairup(x, alv, 2, 3, ((c0 + 2) >> t) & 1);
                    break;
                case 1:
                    pairup(x, alv, 0, 2, ((c0 + 0) >> t) & 1);
                    pairup(x, alv, 1, 3, ((c0 + 1) >> t) & 1);
                    break;
                case 2: crossup<4>  (x, alv, c0, t); break;
                case 3: crossup<8>  (x, alv, c0, t); break;
                case 4: crossup<16> (x, alv, c0, t); break;
                case 5: crossup<32> (x, alv, c0, t); break;
                case 6: crossup<64> (x, alv, c0, t); break;
                case 7: crossup<128>(x, alv, c0, t); break;
                default: {
                    const int m = 1 << s;
                    __syncthreads();
                    *(float4*)&xs[c0] = *(float4*)&x[0];
                    __syncthreads();
                    float xq[4];
                    *(float4*)&xq[0] = *(const float4*)&xs[c0 ^ m];
                    const int flip = ((((c0 >> s) & 1) ^ ((c0 >> t) & 1)) << 31);
                    #pragma unroll
                    for (int j = 0; j < 4; ++j) {
                        const float dv = xq[j] - x[j];
                        const float a  = sigm(bxor(dv, flip));
                        alv[j] = a;
                        x[j]   = fmaf(a, x[j] - xq[j], xq[j]);
                    }
                } break;
            }
            *(float4*)ap = *(float4*)&alv[0];
            ap += NN;
        }
    }

    *(float4*)(out + batch * NN + c0) = *(float4*)&x[0];
}

// ============ Consumer: progressive-width sparse rows, lane-minor ===========
// State: v[2][j], col = W + j*64 + lane, active j in [0, W64).
// Widening 128->256->512->1024 is a register rename (j-shift) + zero-fill.
template<int W64, int DJ>
__device__ __forceinline__ void pairJ(float (&v)[2][16], const float (&al)[16]) {
    #pragma unroll
    for (int r = 0; r < 2; ++r)
        #pragma unroll
        for (int j = 0; j < W64; ++j)
            if ((j & DJ) == 0) {
                const int jl = j, jh = j | DJ;
                const float a  = al[jl];            // == al[jh]
                const float dv = v[r][jl] - v[r][jh];
                const float lo = v[r][jl];
                v[r][jl] = fmaf( a, dv, v[r][jh]);  // a*lo + (1-a)*hi
                v[r][jh] = fmaf(-a, dv, lo);        // (1-a)*lo + a*hi
            }
}
template<int W64, int D>
__device__ __forceinline__ void laneX(float (&v)[2][16], const float (&al)[16]) {
    #pragma unroll
    for (int r = 0; r < 2; ++r)
        #pragma unroll
        for (int j = 0; j < W64; ++j) {
            const float p = lshuf<D>(v[r][j]);
            v[r][j] = fmaf(al[j], v[r][j] - p, p);
        }
}
template<int W64>
__device__ __forceinline__ void loadA(float (&al)[16], const float* __restrict__ ap) {
    #pragma unroll
    for (int j = 0; j < W64; ++j) al[j] = ap[j * 64];
}

__global__ __launch_bounds__(256) void diffsort_rows3(
    const float* __restrict__ al_g,
    float*       __restrict__ out)
{
    const int tid   = threadIdx.x;
    const int lane  = tid & 63;
    const int wave  = tid >> 6;
    const int batch = blockIdx.x >> 7;     // 128 blocks per batch
    const int rgrp  = blockIdx.x & 127;    // 8 rows per block
    const int R0    = rgrp * 8 + wave * 2; // 2 rows per wave
    const int WA    = (R0 >> 7) << 7;      // 128-window base
    const int W7    = (R0 >> 8) << 8;      // 256-window base
    const int W8    = (R0 >> 9) << 9;      // 512-window base

    float v[2][16];
    #pragma unroll
    for (int r = 0; r < 2; ++r) {
        const int loc = (R0 + r) & 127;    // row - WA
        v[r][0] = (loc == lane)      ? 1.0f : 0.0f;
        v[r][1] = (loc == lane + 64) ? 1.0f : 0.0f;
    }

    const float* apc = al_g + (size_t)batch * NLAYERS * NN + lane;
    float al[16];

    #define LAX(W64, D)  { loadA<W64>(al, ap); laneX<W64, D>(v, al); ap += NN; }
    #define LPJ(W64, DJ) { loadA<W64>(al, ap); pairJ<W64, DJ>(v, al); ap += NN; }

    // ---- Phase A: blocks 0..6 (28 layers), width 128, j 0..1 ----
    const float* ap = apc + WA;
    LAX(2,1)
    LAX(2,2) LAX(2,1)
    LAX(2,4) LAX(2,2) LAX(2,1)
    LAX(2,8) LAX(2,4) LAX(2,2) LAX(2,1)
    LAX(2,16) LAX(2,8) LAX(2,4) LAX(2,2) LAX(2,1)
    LAX(2,32) LAX(2,16) LAX(2,8) LAX(2,4) LAX(2,2) LAX(2,1)
    LPJ(2,1)  LAX(2,32) LAX(2,16) LAX(2,8) LAX(2,4) LAX(2,2) LAX(2,1)

    // ---- widen to 256 (register rename) ----
    if (WA & 128) {
        #pragma unroll
        for (int r = 0; r < 2; ++r) {
            v[r][2] = v[r][0]; v[r][3] = v[r][1];
            v[r][0] = 0.0f;    v[r][1] = 0.0f;
        }
    } else {
        #pragma unroll
        for (int r = 0; r < 2; ++r) { v[r][2] = 0.0f; v[r][3] = 0.0f; }
    }
    ap = apc + W7 + 28 * NN;

    // ---- Block 7 (8 layers), width 256, j 0..3 ----
    LPJ(4,2) LPJ(4,1) LAX(4,32) LAX(4,16) LAX(4,8) LAX(4,4) LAX(4,2) LAX(4,1)

    // ---- widen to 512 ----
    if (W7 & 256) {
        #pragma unroll
        for (int r = 0; r < 2; ++r) {
            #pragma unroll
            for (int j = 0; j < 4; ++j) { v[r][j+4] = v[r][j]; v[r][j] = 0.0f; }
        }
    } else {
        #pragma unroll
        for (int r = 0; r < 2; ++r)
            #pragma unroll
            for (int j = 4; j < 8; ++j) v[r][j] = 0.0f;
    }
    ap = apc + W8 + 36 * NN;

    // ---- Block 8 (9 layers), width 512, j 0..7 ----
    LPJ(8,4) LPJ(8,2) LPJ(8,1)
    LAX(8,32) LAX(8,16) LAX(8,8) LAX(8,4) LAX(8,2) LAX(8,1)

    // ---- widen to 1024 ----
    if (W8 & 512) {
        #pragma unroll
        for (int r = 0; r < 2; ++r) {
            #pragma unroll
            for (int j = 0; j < 8; ++j) { v[r][j+8] = v[r][j]; v[r][j] = 0.0f; }
        }
    } else {
        #pragma unroll
        for (int r = 0; r < 2; ++r)
            #pragma unroll
            for (int j = 8; j < 16; ++j) v[r][j] = 0.0f;
    }
    ap = apc + 45 * NN;

    // ---- Block 9 (10 layers), width 1024, j 0..15 ----
    LPJ(16,8) LPJ(16,4) LPJ(16,2) LPJ(16,1)
    LAX(16,32) LAX(16,16) LAX(16,8) LAX(16,4) LAX(16,2) LAX(16,1)

    #undef LAX
    #undef LPJ

    // ---- epilogue: col = j*64 + lane, coalesced b32 stores ----
    float* Xo = out + (size_t)NB * NN + (size_t)batch * NN * NN;
    #pragma unroll
    for (int r = 0; r < 2; ++r) {
        float* rowp = Xo + (size_t)(R0 + r) * NN + lane;
        #pragma unroll
        for (int j = 0; j < 16; ++j)
            rowp[j * 64] = v[r][j];
    }
}

extern "C" void kernel_launch(void* const* d_in, const int* in_sizes, int n_in,
                              void* d_out, int out_size, void* d_ws, size_t ws_size,
                              hipStream_t stream) {
    const float* vecs = (const float*)d_in[0];
    float*       out  = (float*)d_out;
    float*       al_g = (float*)d_ws;    // NB*NLAYERS*NN*4 = 1.80 MB

    diffsort_alpha4<<<NB, 256, 0, stream>>>(vecs, out, al_g);
    diffsort_rows3<<<NB * 128, 256, 0, stream>>>(al_g, out);
}